// Round 1
// baseline (1488.474 us; speedup 1.0000x reference)
//
#include <hip/hip_runtime.h>

#define N_NODES 100000
#define N_EDGES 1600000
#define D_IN    256
#define D_OUT   64

// ---------------------------------------------------------------------------
// Kernel 1: support = features @ W   (f32, vector ALU)
// Block = 256 threads (4 waves). Each wave computes 8 rows x 64 cols.
// W staged fully in LDS (64 KB). Feature loads are wave-uniform -> scalar.
// Grid = 100000 / 32 = 3125 blocks.
// ---------------------------------------------------------------------------
__global__ __launch_bounds__(256) void gemm_kernel(const float* __restrict__ feat,
                                                   const float* __restrict__ W,
                                                   float* __restrict__ support) {
    __shared__ float Wl[D_IN][D_OUT];   // 64 KB
    const int tid = threadIdx.x;

    // Stage W: 16384 floats = 4096 float4, 256 threads -> 16 iters, coalesced.
    {
        const float4* W4  = (const float4*)W;
        float4*       Wl4 = (float4*)&Wl[0][0];
        #pragma unroll
        for (int i = 0; i < (D_IN * D_OUT / 4) / 256; ++i)
            Wl4[i * 256 + tid] = W4[i * 256 + tid];
    }
    __syncthreads();

    const int lane = tid & 63;
    const int wave = tid >> 6;
    // Force wave-uniform row base into an SGPR so feature loads scalarize.
    int row0 = __builtin_amdgcn_readfirstlane(blockIdx.x * 32 + wave * 8);

    const float4* f0 = (const float4*)(feat + (size_t)row0 * D_IN);  // 64 float4 per row

    float acc[8];
    #pragma unroll
    for (int r = 0; r < 8; ++r) acc[r] = 0.0f;

    for (int k4 = 0; k4 < D_IN / 4; ++k4) {
        const float wv0 = Wl[4 * k4 + 0][lane];
        const float wv1 = Wl[4 * k4 + 1][lane];
        const float wv2 = Wl[4 * k4 + 2][lane];
        const float wv3 = Wl[4 * k4 + 3][lane];
        #pragma unroll
        for (int r = 0; r < 8; ++r) {
            const float4 f = f0[r * (D_IN / 4) + k4];  // wave-uniform -> s_load_dwordx4
            acc[r] = fmaf(f.x, wv0, acc[r]);
            acc[r] = fmaf(f.y, wv1, acc[r]);
            acc[r] = fmaf(f.z, wv2, acc[r]);
            acc[r] = fmaf(f.w, wv3, acc[r]);
        }
    }

    #pragma unroll
    for (int r = 0; r < 8; ++r)
        support[(size_t)(row0 + r) * D_OUT + lane] = acc[r];
}

// ---------------------------------------------------------------------------
// Kernel 2: edge scatter  out[r] += v * support[c]
// One thread per (edge, 4-col chunk): 16 threads/edge, 25.6M threads.
// unsafeAtomicAdd -> HW global_atomic_add_f32.
// ---------------------------------------------------------------------------
__global__ __launch_bounds__(256) void scatter_kernel(const int*   __restrict__ rows,
                                                      const int*   __restrict__ cols,
                                                      const float* __restrict__ vals,
                                                      const float* __restrict__ support,
                                                      float*       __restrict__ out) {
    const long long gid = (long long)blockIdx.x * 256 + threadIdx.x;
    const int e = (int)(gid >> 4);
    const int p = (int)(gid & 15);
    if (e >= N_EDGES) return;

    const int   r = rows[e];
    const int   c = cols[e];
    const float v = vals[e];

    const float4 s = *(const float4*)(support + (size_t)c * D_OUT + p * 4);
    float* dst = out + (size_t)r * D_OUT + p * 4;

    unsafeAtomicAdd(dst + 0, v * s.x);
    unsafeAtomicAdd(dst + 1, v * s.y);
    unsafeAtomicAdd(dst + 2, v * s.z);
    unsafeAtomicAdd(dst + 3, v * s.w);
}

// ---------------------------------------------------------------------------
// Kernel 3: in-place ReLU on out (6.4M floats = 1.6M float4).
// ---------------------------------------------------------------------------
__global__ __launch_bounds__(256) void relu_kernel(float* __restrict__ out) {
    const int gid = blockIdx.x * 256 + threadIdx.x;   // 6250*256 = 1.6M exact
    float4* p = (float4*)out + gid;
    float4 x = *p;
    x.x = fmaxf(x.x, 0.0f);
    x.y = fmaxf(x.y, 0.0f);
    x.z = fmaxf(x.z, 0.0f);
    x.w = fmaxf(x.w, 0.0f);
    *p = x;
}

extern "C" void kernel_launch(void* const* d_in, const int* in_sizes, int n_in,
                              void* d_out, int out_size, void* d_ws, size_t ws_size,
                              hipStream_t stream) {
    const float* feat = (const float*)d_in[0];
    const float* W    = (const float*)d_in[1];
    const int*   rows = (const int*)d_in[2];
    const int*   cols = (const int*)d_in[3];
    const float* vals = (const float*)d_in[4];
    float*       out  = (float*)d_out;
    float*       support = (float*)d_ws;   // 100000*64*4 = 25.6 MB

    // out must start at zero for the atomic accumulation (harness poisons it).
    hipMemsetAsync(d_out, 0, (size_t)N_NODES * D_OUT * sizeof(float), stream);

    gemm_kernel<<<N_NODES / 32, 256, 0, stream>>>(feat, W, support);

    const long long scatter_threads = (long long)N_EDGES * 16;
    scatter_kernel<<<(int)(scatter_threads / 256), 256, 0, stream>>>(rows, cols, vals, support, out);

    relu_kernel<<<(N_NODES * D_OUT / 4) / 256, 256, 0, stream>>>(out);
}

// Round 2
// 394.812 us; speedup vs baseline: 3.7701x; 3.7701x over previous
//
#include <hip/hip_runtime.h>

#define N_NODES 100000
#define N_EDGES 1600000
#define D_IN    256
#define D_OUT   64

#define SCAN_BLK   1024
#define SCAN_NBLK  ((N_NODES + SCAN_BLK - 1) / SCAN_BLK)   // 98

// ---------------------------------------------------------------------------
// Kernel 1: support = features @ W   (f32, vector ALU)
// ---------------------------------------------------------------------------
__global__ __launch_bounds__(256) void gemm_kernel(const float* __restrict__ feat,
                                                   const float* __restrict__ W,
                                                   float* __restrict__ support) {
    __shared__ float Wl[D_IN][D_OUT];   // 64 KB
    const int tid = threadIdx.x;

    {
        const float4* W4  = (const float4*)W;
        float4*       Wl4 = (float4*)&Wl[0][0];
        #pragma unroll
        for (int i = 0; i < (D_IN * D_OUT / 4) / 256; ++i)
            Wl4[i * 256 + tid] = W4[i * 256 + tid];
    }
    __syncthreads();

    const int lane = tid & 63;
    const int wave = tid >> 6;
    int row0 = __builtin_amdgcn_readfirstlane(blockIdx.x * 32 + wave * 8);

    const float4* f0 = (const float4*)(feat + (size_t)row0 * D_IN);

    float acc[8];
    #pragma unroll
    for (int r = 0; r < 8; ++r) acc[r] = 0.0f;

    for (int k4 = 0; k4 < D_IN / 4; ++k4) {
        const float wv0 = Wl[4 * k4 + 0][lane];
        const float wv1 = Wl[4 * k4 + 1][lane];
        const float wv2 = Wl[4 * k4 + 2][lane];
        const float wv3 = Wl[4 * k4 + 3][lane];
        #pragma unroll
        for (int r = 0; r < 8; ++r) {
            const float4 f = f0[r * (D_IN / 4) + k4];
            acc[r] = fmaf(f.x, wv0, acc[r]);
            acc[r] = fmaf(f.y, wv1, acc[r]);
            acc[r] = fmaf(f.z, wv2, acc[r]);
            acc[r] = fmaf(f.w, wv3, acc[r]);
        }
    }

    #pragma unroll
    for (int r = 0; r < 8; ++r)
        support[(size_t)(row0 + r) * D_OUT + lane] = acc[r];
}

// ---------------------------------------------------------------------------
// Kernel 2: histogram of destination rows (int atomics into counts[]).
// ---------------------------------------------------------------------------
__global__ __launch_bounds__(256) void hist_kernel(const int* __restrict__ rows,
                                                   int* __restrict__ counts) {
    const int e = blockIdx.x * 256 + threadIdx.x;
    if (e < N_EDGES) atomicAdd(&counts[rows[e]], 1);
}

// ---------------------------------------------------------------------------
// Kernel 3a: per-block exclusive scan (Hillis-Steele in LDS), emit block sums.
// ---------------------------------------------------------------------------
__global__ __launch_bounds__(SCAN_BLK) void scan1_kernel(const int* __restrict__ counts,
                                                         int* __restrict__ excl_out,
                                                         int* __restrict__ blk_sums) {
    __shared__ int s[SCAN_BLK];
    const int tid = threadIdx.x;
    const int i   = blockIdx.x * SCAN_BLK + tid;
    const int val = (i < N_NODES) ? counts[i] : 0;
    s[tid] = val;
    __syncthreads();
    for (int off = 1; off < SCAN_BLK; off <<= 1) {
        int t = 0;
        if (tid >= off) t = s[tid - off];
        __syncthreads();
        s[tid] += t;
        __syncthreads();
    }
    const int incl = s[tid];
    if (i < N_NODES) excl_out[i] = incl - val;
    if (tid == SCAN_BLK - 1) blk_sums[blockIdx.x] = incl;
}

// ---------------------------------------------------------------------------
// Kernel 3b: scan the 98 block sums (one block of 128).
// ---------------------------------------------------------------------------
__global__ __launch_bounds__(128) void scan2_kernel(int* __restrict__ blk_sums,
                                                    int* __restrict__ blk_prefix) {
    __shared__ int s[128];
    const int tid = threadIdx.x;
    const int val = (tid < SCAN_NBLK) ? blk_sums[tid] : 0;
    s[tid] = val;
    __syncthreads();
    for (int off = 1; off < 128; off <<= 1) {
        int t = 0;
        if (tid >= off) t = s[tid - off];
        __syncthreads();
        s[tid] += t;
        __syncthreads();
    }
    blk_prefix[tid] = s[tid] - val;   // exclusive
}

// ---------------------------------------------------------------------------
// Kernel 3c: add block prefixes -> final offsets; also init cursor copy.
// ---------------------------------------------------------------------------
__global__ __launch_bounds__(SCAN_BLK) void scan3_kernel(int* __restrict__ offsets,
                                                         const int* __restrict__ blk_prefix,
                                                         int* __restrict__ cursor) {
    const int i = blockIdx.x * SCAN_BLK + threadIdx.x;
    if (i < N_NODES) {
        const int off = offsets[i] + blk_prefix[blockIdx.x];
        offsets[i] = off;
        cursor[i]  = off;
    }
    if (i == 0) offsets[N_NODES] = N_EDGES;
}

// ---------------------------------------------------------------------------
// Kernel 4: bucket edges by destination row (int atomic on cursor).
// ---------------------------------------------------------------------------
__global__ __launch_bounds__(256) void reorder_kernel(const int*   __restrict__ rows,
                                                      const int*   __restrict__ cols,
                                                      const float* __restrict__ vals,
                                                      int*   __restrict__ cursor,
                                                      int*   __restrict__ sorted_col,
                                                      float* __restrict__ sorted_val) {
    const int e = blockIdx.x * 256 + threadIdx.x;
    if (e >= N_EDGES) return;
    const int r   = rows[e];
    const int pos = atomicAdd(&cursor[r], 1);
    sorted_col[pos] = cols[e];
    sorted_val[pos] = vals[e];
}

// ---------------------------------------------------------------------------
// Kernel 5: per-row gather-reduce + fused ReLU. One wave per row.
// lane = output column; edges of the row walked serially (wave-uniform).
// ---------------------------------------------------------------------------
__global__ __launch_bounds__(256) void reduce_kernel(const int*   __restrict__ offsets,
                                                     const int*   __restrict__ sorted_col,
                                                     const float* __restrict__ sorted_val,
                                                     const float* __restrict__ support,
                                                     float*       __restrict__ out) {
    const int lane = threadIdx.x & 63;
    int row = blockIdx.x * 4 + (threadIdx.x >> 6);
    row = __builtin_amdgcn_readfirstlane(row);   // wave-uniform -> scalar loads below
    if (row >= N_NODES) return;

    const int start = offsets[row];
    const int end   = offsets[row + 1];

    float acc0 = 0.0f, acc1 = 0.0f;
    int e = start;
    for (; e + 1 < end; e += 2) {
        const int   c0 = sorted_col[e];
        const int   c1 = sorted_col[e + 1];
        const float v0 = sorted_val[e];
        const float v1 = sorted_val[e + 1];
        acc0 = fmaf(v0, support[(size_t)c0 * D_OUT + lane], acc0);
        acc1 = fmaf(v1, support[(size_t)c1 * D_OUT + lane], acc1);
    }
    if (e < end) {
        const int   c = sorted_col[e];
        const float v = sorted_val[e];
        acc0 = fmaf(v, support[(size_t)c * D_OUT + lane], acc0);
    }
    out[(size_t)row * D_OUT + lane] = fmaxf(acc0 + acc1, 0.0f);
}

extern "C" void kernel_launch(void* const* d_in, const int* in_sizes, int n_in,
                              void* d_out, int out_size, void* d_ws, size_t ws_size,
                              hipStream_t stream) {
    const float* feat = (const float*)d_in[0];
    const float* W    = (const float*)d_in[1];
    const int*   rows = (const int*)d_in[2];
    const int*   cols = (const int*)d_in[3];
    const float* vals = (const float*)d_in[4];
    float*       out  = (float*)d_out;

    // Workspace layout (all 16B-aligned, units of float/int = 4B):
    float* support    = (float*)d_ws;                       // 6,400,000
    int*   offsets    = (int*)(support + 6400000);          // 100,004 (N+1 padded)
    int*   cursor     = (int*)(offsets + 100004);           // 100,000 (also histogram counts)
    int*   blk_sums   = (int*)(cursor + 100000);            // 128
    int*   blk_prefix = (int*)(blk_sums + 128);             // 128
    int*   sorted_col = (int*)(blk_prefix + 128);           // 1,600,000
    float* sorted_val = (float*)(sorted_col + 1600000);     // 1,600,000
    // total ~39.6 MB

    // 1) dense GEMM
    gemm_kernel<<<N_NODES / 32, 256, 0, stream>>>(feat, W, support);

    // 2) CSR build: counts (in cursor) -> scan -> offsets, cursor
    hipMemsetAsync(cursor, 0, N_NODES * sizeof(int), stream);
    hist_kernel<<<(N_EDGES + 255) / 256, 256, 0, stream>>>(rows, cursor);
    scan1_kernel<<<SCAN_NBLK, SCAN_BLK, 0, stream>>>(cursor, offsets, blk_sums);
    scan2_kernel<<<1, 128, 0, stream>>>(blk_sums, blk_prefix);
    scan3_kernel<<<SCAN_NBLK, SCAN_BLK, 0, stream>>>(offsets, blk_prefix, cursor);

    // 3) bucket edges by row
    reorder_kernel<<<(N_EDGES + 255) / 256, 256, 0, stream>>>(rows, cols, vals,
                                                              cursor, sorted_col, sorted_val);

    // 4) per-row gather-reduce + ReLU
    reduce_kernel<<<(N_NODES + 3) / 4, 256, 0, stream>>>(offsets, sorted_col, sorted_val,
                                                         support, out);
}

// Round 3
// 358.412 us; speedup vs baseline: 4.1530x; 1.1016x over previous
//
#include <hip/hip_runtime.h>

#define N_NODES 100000
#define N_EDGES 1600000
#define D_IN    256
#define D_OUT   64

#define SCAN_BLK   1024
#define SCAN_NBLK  ((N_NODES + SCAN_BLK - 1) / SCAN_BLK)   // 98

// ---------------------------------------------------------------------------
// Kernel 1: support = features @ W   (f32, vector ALU)
// Block = 1024 threads (16 waves) sharing one 64KB W-tile in LDS:
//   LDS/CU = 2 blocks x 64KB -> 32 waves/CU (100% occupancy) vs 8 before.
// Each wave: 8 rows x 64 cols; feature loads wave-uniform -> scalar (s_load).
// ---------------------------------------------------------------------------
__global__ __launch_bounds__(1024) void gemm_kernel(const float* __restrict__ feat,
                                                    const float* __restrict__ W,
                                                    float* __restrict__ support) {
    __shared__ float Wl[D_IN][D_OUT];   // 64 KB
    const int tid = threadIdx.x;

    {
        const float4* W4  = (const float4*)W;
        float4*       Wl4 = (float4*)&Wl[0][0];
        #pragma unroll
        for (int i = 0; i < (D_IN * D_OUT / 4) / 1024; ++i)
            Wl4[i * 1024 + tid] = W4[i * 1024 + tid];
    }
    __syncthreads();

    const int lane = tid & 63;
    const int wave = tid >> 6;
    // 128 rows/block, 8 rows/wave. Guard whole-wave (100000 % 8 == 0).
    int row0 = __builtin_amdgcn_readfirstlane(blockIdx.x * 128 + wave * 8);
    if (row0 >= N_NODES) return;

    const float4* f0 = (const float4*)(feat + (size_t)row0 * D_IN);

    float acc[8];
    #pragma unroll
    for (int r = 0; r < 8; ++r) acc[r] = 0.0f;

    for (int k4 = 0; k4 < D_IN / 4; ++k4) {
        const float wv0 = Wl[4 * k4 + 0][lane];
        const float wv1 = Wl[4 * k4 + 1][lane];
        const float wv2 = Wl[4 * k4 + 2][lane];
        const float wv3 = Wl[4 * k4 + 3][lane];
        #pragma unroll
        for (int r = 0; r < 8; ++r) {
            const float4 f = f0[r * (D_IN / 4) + k4];   // wave-uniform -> s_load_dwordx4
            acc[r] = fmaf(f.x, wv0, acc[r]);
            acc[r] = fmaf(f.y, wv1, acc[r]);
            acc[r] = fmaf(f.z, wv2, acc[r]);
            acc[r] = fmaf(f.w, wv3, acc[r]);
        }
    }

    #pragma unroll
    for (int r = 0; r < 8; ++r)
        support[(size_t)(row0 + r) * D_OUT + lane] = acc[r];
}

// ---------------------------------------------------------------------------
// Kernel 2: histogram of destination rows (int atomics into counts[]).
// ---------------------------------------------------------------------------
__global__ __launch_bounds__(256) void hist_kernel(const int* __restrict__ rows,
                                                   int* __restrict__ counts) {
    const int e = blockIdx.x * 256 + threadIdx.x;
    if (e < N_EDGES) atomicAdd(&counts[rows[e]], 1);
}

// ---------------------------------------------------------------------------
// Kernel 3a: per-block exclusive scan (Hillis-Steele in LDS), emit block sums.
// ---------------------------------------------------------------------------
__global__ __launch_bounds__(SCAN_BLK) void scan1_kernel(const int* __restrict__ counts,
                                                         int* __restrict__ excl_out,
                                                         int* __restrict__ blk_sums) {
    __shared__ int s[SCAN_BLK];
    const int tid = threadIdx.x;
    const int i   = blockIdx.x * SCAN_BLK + tid;
    const int val = (i < N_NODES) ? counts[i] : 0;
    s[tid] = val;
    __syncthreads();
    for (int off = 1; off < SCAN_BLK; off <<= 1) {
        int t = 0;
        if (tid >= off) t = s[tid - off];
        __syncthreads();
        s[tid] += t;
        __syncthreads();
    }
    const int incl = s[tid];
    if (i < N_NODES) excl_out[i] = incl - val;
    if (tid == SCAN_BLK - 1) blk_sums[blockIdx.x] = incl;
}

// ---------------------------------------------------------------------------
// Kernel 3b: scan the 98 block sums (one block of 128).
// ---------------------------------------------------------------------------
__global__ __launch_bounds__(128) void scan2_kernel(int* __restrict__ blk_sums,
                                                    int* __restrict__ blk_prefix) {
    __shared__ int s[128];
    const int tid = threadIdx.x;
    const int val = (tid < SCAN_NBLK) ? blk_sums[tid] : 0;
    s[tid] = val;
    __syncthreads();
    for (int off = 1; off < 128; off <<= 1) {
        int t = 0;
        if (tid >= off) t = s[tid - off];
        __syncthreads();
        s[tid] += t;
        __syncthreads();
    }
    blk_prefix[tid] = s[tid] - val;   // exclusive
}

// ---------------------------------------------------------------------------
// Kernel 3c: add block prefixes -> final offsets; also init cursor copy.
// ---------------------------------------------------------------------------
__global__ __launch_bounds__(SCAN_BLK) void scan3_kernel(int* __restrict__ offsets,
                                                         const int* __restrict__ blk_prefix,
                                                         int* __restrict__ cursor) {
    const int i = blockIdx.x * SCAN_BLK + threadIdx.x;
    if (i < N_NODES) {
        const int off = offsets[i] + blk_prefix[blockIdx.x];
        offsets[i] = off;
        cursor[i]  = off;
    }
    if (i == 0) offsets[N_NODES] = N_EDGES;
}

// ---------------------------------------------------------------------------
// Kernel 4: bucket edges by destination row (int atomic on cursor).
// ---------------------------------------------------------------------------
__global__ __launch_bounds__(256) void reorder_kernel(const int*   __restrict__ rows,
                                                      const int*   __restrict__ cols,
                                                      const float* __restrict__ vals,
                                                      int*   __restrict__ cursor,
                                                      int*   __restrict__ sorted_col,
                                                      float* __restrict__ sorted_val) {
    const int e = blockIdx.x * 256 + threadIdx.x;
    if (e >= N_EDGES) return;
    const int r   = rows[e];
    const int pos = atomicAdd(&cursor[r], 1);
    sorted_col[pos] = cols[e];
    sorted_val[pos] = vals[e];
}

// ---------------------------------------------------------------------------
// Kernel 5: per-row gather-reduce + fused ReLU. One wave per row.
// lane = output column; 4 independent accumulator chains for MLP.
// ---------------------------------------------------------------------------
__global__ __launch_bounds__(256) void reduce_kernel(const int*   __restrict__ offsets,
                                                     const int*   __restrict__ sorted_col,
                                                     const float* __restrict__ sorted_val,
                                                     const float* __restrict__ support,
                                                     float*       __restrict__ out) {
    const int lane = threadIdx.x & 63;
    int row = blockIdx.x * 4 + (threadIdx.x >> 6);
    row = __builtin_amdgcn_readfirstlane(row);
    if (row >= N_NODES) return;

    const int start = offsets[row];
    const int end   = offsets[row + 1];

    float acc0 = 0.0f, acc1 = 0.0f, acc2 = 0.0f, acc3 = 0.0f;
    int e = start;
    for (; e + 3 < end; e += 4) {
        const int   c0 = sorted_col[e];
        const int   c1 = sorted_col[e + 1];
        const int   c2 = sorted_col[e + 2];
        const int   c3 = sorted_col[e + 3];
        const float v0 = sorted_val[e];
        const float v1 = sorted_val[e + 1];
        const float v2 = sorted_val[e + 2];
        const float v3 = sorted_val[e + 3];
        acc0 = fmaf(v0, support[(size_t)c0 * D_OUT + lane], acc0);
        acc1 = fmaf(v1, support[(size_t)c1 * D_OUT + lane], acc1);
        acc2 = fmaf(v2, support[(size_t)c2 * D_OUT + lane], acc2);
        acc3 = fmaf(v3, support[(size_t)c3 * D_OUT + lane], acc3);
    }
    for (; e < end; ++e) {
        const int   c = sorted_col[e];
        const float v = sorted_val[e];
        acc0 = fmaf(v, support[(size_t)c * D_OUT + lane], acc0);
    }
    out[(size_t)row * D_OUT + lane] = fmaxf((acc0 + acc1) + (acc2 + acc3), 0.0f);
}

extern "C" void kernel_launch(void* const* d_in, const int* in_sizes, int n_in,
                              void* d_out, int out_size, void* d_ws, size_t ws_size,
                              hipStream_t stream) {
    const float* feat = (const float*)d_in[0];
    const float* W    = (const float*)d_in[1];
    const int*   rows = (const int*)d_in[2];
    const int*   cols = (const int*)d_in[3];
    const float* vals = (const float*)d_in[4];
    float*       out  = (float*)d_out;

    // Workspace layout:
    float* support    = (float*)d_ws;                       // 6,400,000
    int*   offsets    = (int*)(support + 6400000);          // 100,004
    int*   cursor     = (int*)(offsets + 100004);           // 100,000 (also histogram)
    int*   blk_sums   = (int*)(cursor + 100000);            // 128
    int*   blk_prefix = (int*)(blk_sums + 128);             // 128
    int*   sorted_col = (int*)(blk_prefix + 128);           // 1,600,000
    float* sorted_val = (float*)(sorted_col + 1600000);     // 1,600,000

    // 1) dense GEMM
    gemm_kernel<<<(N_NODES + 127) / 128, 1024, 0, stream>>>(feat, W, support);

    // 2) CSR build
    hipMemsetAsync(cursor, 0, N_NODES * sizeof(int), stream);
    hist_kernel<<<(N_EDGES + 255) / 256, 256, 0, stream>>>(rows, cursor);
    scan1_kernel<<<SCAN_NBLK, SCAN_BLK, 0, stream>>>(cursor, offsets, blk_sums);
    scan2_kernel<<<1, 128, 0, stream>>>(blk_sums, blk_prefix);
    scan3_kernel<<<SCAN_NBLK, SCAN_BLK, 0, stream>>>(offsets, blk_prefix, cursor);

    // 3) bucket edges by row
    reorder_kernel<<<(N_EDGES + 255) / 256, 256, 0, stream>>>(rows, cols, vals,
                                                              cursor, sorted_col, sorted_val);

    // 4) per-row gather-reduce + ReLU
    reduce_kernel<<<(N_NODES + 3) / 4, 256, 0, stream>>>(offsets, sorted_col, sorted_val,
                                                         support, out);
}

// Round 4
// 284.416 us; speedup vs baseline: 5.2334x; 1.2602x over previous
//
#include <hip/hip_runtime.h>

#define N_NODES 100000
#define N_EDGES 1600000
#define D_IN    256
#define D_OUT   64

#define SCAN_BLK   1024
#define SCAN_NBLK  ((N_NODES + SCAN_BLK - 1) / SCAN_BLK)   // 98

typedef __attribute__((ext_vector_type(8))) short short8_t;  // 8 bf16 = 4 VGPRs
typedef __attribute__((ext_vector_type(4))) float f32x4;

// f32 -> bf16 round-to-nearest-even (bit idiom; inputs are finite).
static __device__ __forceinline__ unsigned short f2bf(float f) {
    unsigned u = __builtin_bit_cast(unsigned, f);
    unsigned r = u + 0x7FFFu + ((u >> 16) & 1u);
    return (unsigned short)(r >> 16);
}

// ---------------------------------------------------------------------------
// Kernel 1: support = features @ W via mfma_f32_16x16x32_bf16.
// Block = 256 thr (4 waves), 64 rows/block, full N=64, K=256 in 8 steps.
// W pre-fragmented into LDS once per block (32 KB):
//   Wf[s][nt][lane] = 8 bf16 {W[s*32+(lane>>4)*8+e][nt*16+(lane&15)]}.
// A-fragments loaded directly from global (2x float4/lane) + in-reg cvt.
// Fragment layouts (m89-verified family):
//   A[i][k]: i=lane&15, k=(lane>>4)*8+e
//   B[k][j]: j=lane&15, k=(lane>>4)*8+e
//   D[i][j]: j=lane&15, i=(lane>>4)*4+reg
// ---------------------------------------------------------------------------
__global__ __launch_bounds__(256) void gemm_kernel(const float* __restrict__ feat,
                                                   const float* __restrict__ W,
                                                   float* __restrict__ support) {
    __shared__ unsigned short Wf[2048 * 8];   // 32 KB: 8 ksteps x 4 ntiles x 64 lanes x 8 bf16
    const int tid = threadIdx.x;

    // --- Fill W fragments: 2048 slots, 8 per thread ---
    #pragma unroll
    for (int i = 0; i < 8; ++i) {
        const int slot = i * 256 + tid;
        const int s  = slot >> 8;          // kstep
        const int nt = (slot >> 6) & 3;    // n-tile
        const int l  = slot & 63;          // lane it serves
        const int kbase = s * 32 + ((l >> 4) * 8);
        const int col   = nt * 16 + (l & 15);
        unsigned short tmp[8];
        #pragma unroll
        for (int e = 0; e < 8; ++e)
            tmp[e] = f2bf(W[(size_t)(kbase + e) * D_OUT + col]);
        *(short8_t*)&Wf[slot * 8] = *(short8_t*)tmp;
    }
    __syncthreads();

    const int lane = tid & 63;
    const int wave = tid >> 6;
    const int row0 = blockIdx.x * 64 + wave * 16;   // 16 rows per wave
    if (row0 >= N_NODES) return;                     // tail waves (after barrier: safe)

    // Per-lane A row pointer: row = row0 + (lane&15), k-base = (lane>>4)*8
    const float* arow = feat + (size_t)(row0 + (lane & 15)) * D_IN + ((lane >> 4) * 8);

    f32x4 acc[4];
    #pragma unroll
    for (int nt = 0; nt < 4; ++nt) acc[nt] = (f32x4){0.f, 0.f, 0.f, 0.f};

    #pragma unroll
    for (int s = 0; s < 8; ++s) {
        const float4 a0 = *(const float4*)(arow + s * 32);
        const float4 a1 = *(const float4*)(arow + s * 32 + 4);
        unsigned short af[8];
        af[0] = f2bf(a0.x); af[1] = f2bf(a0.y); af[2] = f2bf(a0.z); af[3] = f2bf(a0.w);
        af[4] = f2bf(a1.x); af[5] = f2bf(a1.y); af[6] = f2bf(a1.z); af[7] = f2bf(a1.w);
        const short8_t av = *(short8_t*)af;
        #pragma unroll
        for (int nt = 0; nt < 4; ++nt) {
            const short8_t bv = *(short8_t*)&Wf[((s * 4 + nt) * 64 + lane) * 8];
            acc[nt] = __builtin_amdgcn_mfma_f32_16x16x32_bf16(av, bv, acc[nt], 0, 0, 0);
        }
    }

    // D[i][j]: j = lane&15, i = (lane>>4)*4 + reg
    #pragma unroll
    for (int nt = 0; nt < 4; ++nt) {
        #pragma unroll
        for (int reg = 0; reg < 4; ++reg) {
            const int row = row0 + (lane >> 4) * 4 + reg;
            const int col = nt * 16 + (lane & 15);
            support[(size_t)row * D_OUT + col] = acc[nt][reg];
        }
    }
}

// ---------------------------------------------------------------------------
// Kernel 2: histogram of destination rows (int atomics into counts[]).
// ---------------------------------------------------------------------------
__global__ __launch_bounds__(256) void hist_kernel(const int* __restrict__ rows,
                                                   int* __restrict__ counts) {
    const int e = blockIdx.x * 256 + threadIdx.x;
    if (e < N_EDGES) atomicAdd(&counts[rows[e]], 1);
}

// ---------------------------------------------------------------------------
// Kernel 3a: per-block exclusive scan (Hillis-Steele in LDS), emit block sums.
// ---------------------------------------------------------------------------
__global__ __launch_bounds__(SCAN_BLK) void scan1_kernel(const int* __restrict__ counts,
                                                         int* __restrict__ excl_out,
                                                         int* __restrict__ blk_sums) {
    __shared__ int s[SCAN_BLK];
    const int tid = threadIdx.x;
    const int i   = blockIdx.x * SCAN_BLK + tid;
    const int val = (i < N_NODES) ? counts[i] : 0;
    s[tid] = val;
    __syncthreads();
    for (int off = 1; off < SCAN_BLK; off <<= 1) {
        int t = 0;
        if (tid >= off) t = s[tid - off];
        __syncthreads();
        s[tid] += t;
        __syncthreads();
    }
    const int incl = s[tid];
    if (i < N_NODES) excl_out[i] = incl - val;
    if (tid == SCAN_BLK - 1) blk_sums[blockIdx.x] = incl;
}

// ---------------------------------------------------------------------------
// Kernel 3b: scan the 98 block sums (one block of 128).
// ---------------------------------------------------------------------------
__global__ __launch_bounds__(128) void scan2_kernel(int* __restrict__ blk_sums,
                                                    int* __restrict__ blk_prefix) {
    __shared__ int s[128];
    const int tid = threadIdx.x;
    const int val = (tid < SCAN_NBLK) ? blk_sums[tid] : 0;
    s[tid] = val;
    __syncthreads();
    for (int off = 1; off < 128; off <<= 1) {
        int t = 0;
        if (tid >= off) t = s[tid - off];
        __syncthreads();
        s[tid] += t;
        __syncthreads();
    }
    blk_prefix[tid] = s[tid] - val;   // exclusive
}

// ---------------------------------------------------------------------------
// Kernel 3c: add block prefixes -> final offsets; also init cursor copy.
// ---------------------------------------------------------------------------
__global__ __launch_bounds__(SCAN_BLK) void scan3_kernel(int* __restrict__ offsets,
                                                         const int* __restrict__ blk_prefix,
                                                         int* __restrict__ cursor) {
    const int i = blockIdx.x * SCAN_BLK + threadIdx.x;
    if (i < N_NODES) {
        const int off = offsets[i] + blk_prefix[blockIdx.x];
        offsets[i] = off;
        cursor[i]  = off;
    }
    if (i == 0) offsets[N_NODES] = N_EDGES;
}

// ---------------------------------------------------------------------------
// Kernel 4: bucket edges by destination row (int atomic on cursor).
// ---------------------------------------------------------------------------
__global__ __launch_bounds__(256) void reorder_kernel(const int*   __restrict__ rows,
                                                      const int*   __restrict__ cols,
                                                      const float* __restrict__ vals,
                                                      int*   __restrict__ cursor,
                                                      int*   __restrict__ sorted_col,
                                                      float* __restrict__ sorted_val) {
    const int e = blockIdx.x * 256 + threadIdx.x;
    if (e >= N_EDGES) return;
    const int r   = rows[e];
    const int pos = atomicAdd(&cursor[r], 1);
    sorted_col[pos] = cols[e];
    sorted_val[pos] = vals[e];
}

// ---------------------------------------------------------------------------
// Kernel 5: per-row gather-reduce + fused ReLU. One wave per row.
// lane = output column; 4 independent accumulator chains for MLP.
// ---------------------------------------------------------------------------
__global__ __launch_bounds__(256) void reduce_kernel(const int*   __restrict__ offsets,
                                                     const int*   __restrict__ sorted_col,
                                                     const float* __restrict__ sorted_val,
                                                     const float* __restrict__ support,
                                                     float*       __restrict__ out) {
    const int lane = threadIdx.x & 63;
    int row = blockIdx.x * 4 + (threadIdx.x >> 6);
    row = __builtin_amdgcn_readfirstlane(row);
    if (row >= N_NODES) return;

    const int start = offsets[row];
    const int end   = offsets[row + 1];

    float acc0 = 0.0f, acc1 = 0.0f, acc2 = 0.0f, acc3 = 0.0f;
    int e = start;
    for (; e + 3 < end; e += 4) {
        const int   c0 = sorted_col[e];
        const int   c1 = sorted_col[e + 1];
        const int   c2 = sorted_col[e + 2];
        const int   c3 = sorted_col[e + 3];
        const float v0 = sorted_val[e];
        const float v1 = sorted_val[e + 1];
        const float v2 = sorted_val[e + 2];
        const float v3 = sorted_val[e + 3];
        acc0 = fmaf(v0, support[(size_t)c0 * D_OUT + lane], acc0);
        acc1 = fmaf(v1, support[(size_t)c1 * D_OUT + lane], acc1);
        acc2 = fmaf(v2, support[(size_t)c2 * D_OUT + lane], acc2);
        acc3 = fmaf(v3, support[(size_t)c3 * D_OUT + lane], acc3);
    }
    for (; e < end; ++e) {
        const int   c = sorted_col[e];
        const float v = sorted_val[e];
        acc0 = fmaf(v, support[(size_t)c * D_OUT + lane], acc0);
    }
    out[(size_t)row * D_OUT + lane] = fmaxf((acc0 + acc1) + (acc2 + acc3), 0.0f);
}

extern "C" void kernel_launch(void* const* d_in, const int* in_sizes, int n_in,
                              void* d_out, int out_size, void* d_ws, size_t ws_size,
                              hipStream_t stream) {
    const float* feat = (const float*)d_in[0];
    const float* W    = (const float*)d_in[1];
    const int*   rows = (const int*)d_in[2];
    const int*   cols = (const int*)d_in[3];
    const float* vals = (const float*)d_in[4];
    float*       out  = (float*)d_out;

    // Workspace layout:
    float* support    = (float*)d_ws;                       // 6,400,000
    int*   offsets    = (int*)(support + 6400000);          // 100,004
    int*   cursor     = (int*)(offsets + 100004);           // 100,000 (also histogram)
    int*   blk_sums   = (int*)(cursor + 100000);            // 128
    int*   blk_prefix = (int*)(blk_sums + 128);             // 128
    int*   sorted_col = (int*)(blk_prefix + 128);           // 1,600,000
    float* sorted_val = (float*)(sorted_col + 1600000);     // 1,600,000

    // 1) dense GEMM (bf16 MFMA)
    gemm_kernel<<<(N_NODES + 63) / 64, 256, 0, stream>>>(feat, W, support);

    // 2) CSR build
    hipMemsetAsync(cursor, 0, N_NODES * sizeof(int), stream);
    hist_kernel<<<(N_EDGES + 255) / 256, 256, 0, stream>>>(rows, cursor);
    scan1_kernel<<<SCAN_NBLK, SCAN_BLK, 0, stream>>>(cursor, offsets, blk_sums);
    scan2_kernel<<<1, 128, 0, stream>>>(blk_sums, blk_prefix);
    scan3_kernel<<<SCAN_NBLK, SCAN_BLK, 0, stream>>>(offsets, blk_prefix, cursor);

    // 3) bucket edges by row
    reorder_kernel<<<(N_EDGES + 255) / 256, 256, 0, stream>>>(rows, cols, vals,
                                                              cursor, sorted_col, sorted_val);

    // 4) per-row gather-reduce + ReLU
    reduce_kernel<<<(N_NODES + 3) / 4, 256, 0, stream>>>(offsets, sorted_col, sorted_val,
                                                         support, out);
}

// Round 5
// 277.747 us; speedup vs baseline: 5.3591x; 1.0240x over previous
//
#include <hip/hip_runtime.h>

#define N_NODES 100000
#define N_EDGES 1600000
#define D_IN    256
#define D_OUT   64

#define SCAN_BLK   1024
#define SCAN_NBLK  ((N_NODES + SCAN_BLK - 1) / SCAN_BLK)   // 98

typedef __attribute__((ext_vector_type(8))) short short8_t;  // 8 bf16 = 4 VGPRs
typedef __attribute__((ext_vector_type(4))) float f32x4;

// f32 -> bf16 round-to-nearest-even (bit idiom; inputs are finite).
static __device__ __forceinline__ unsigned short f2bf(float f) {
    unsigned u = __builtin_bit_cast(unsigned, f);
    unsigned r = u + 0x7FFFu + ((u >> 16) & 1u);
    return (unsigned short)(r >> 16);
}

// ---------------------------------------------------------------------------
// Kernel 1: support = features @ W via mfma_f32_16x16x32_bf16.
// Block = 256 thr (4 waves), 64 rows/block, full N=64, K=256 in 8 steps.
// ---------------------------------------------------------------------------
__global__ __launch_bounds__(256) void gemm_kernel(const float* __restrict__ feat,
                                                   const float* __restrict__ W,
                                                   float* __restrict__ support) {
    __shared__ unsigned short Wf[2048 * 8];   // 32 KB
    const int tid = threadIdx.x;

    #pragma unroll
    for (int i = 0; i < 8; ++i) {
        const int slot = i * 256 + tid;
        const int s  = slot >> 8;          // kstep
        const int nt = (slot >> 6) & 3;    // n-tile
        const int l  = slot & 63;          // lane it serves
        const int kbase = s * 32 + ((l >> 4) * 8);
        const int col   = nt * 16 + (l & 15);
        unsigned short tmp[8];
        #pragma unroll
        for (int e = 0; e < 8; ++e)
            tmp[e] = f2bf(W[(size_t)(kbase + e) * D_OUT + col]);
        *(short8_t*)&Wf[slot * 8] = *(short8_t*)tmp;
    }
    __syncthreads();

    const int lane = tid & 63;
    const int wave = tid >> 6;
    const int row0 = blockIdx.x * 64 + wave * 16;   // 16 rows per wave
    if (row0 >= N_NODES) return;

    const float* arow = feat + (size_t)(row0 + (lane & 15)) * D_IN + ((lane >> 4) * 8);

    f32x4 acc[4];
    #pragma unroll
    for (int nt = 0; nt < 4; ++nt) acc[nt] = (f32x4){0.f, 0.f, 0.f, 0.f};

    #pragma unroll
    for (int s = 0; s < 8; ++s) {
        const float4 a0 = *(const float4*)(arow + s * 32);
        const float4 a1 = *(const float4*)(arow + s * 32 + 4);
        unsigned short af[8];
        af[0] = f2bf(a0.x); af[1] = f2bf(a0.y); af[2] = f2bf(a0.z); af[3] = f2bf(a0.w);
        af[4] = f2bf(a1.x); af[5] = f2bf(a1.y); af[6] = f2bf(a1.z); af[7] = f2bf(a1.w);
        const short8_t av = *(short8_t*)af;
        #pragma unroll
        for (int nt = 0; nt < 4; ++nt) {
            const short8_t bv = *(short8_t*)&Wf[((s * 4 + nt) * 64 + lane) * 8];
            acc[nt] = __builtin_amdgcn_mfma_f32_16x16x32_bf16(av, bv, acc[nt], 0, 0, 0);
        }
    }

    #pragma unroll
    for (int nt = 0; nt < 4; ++nt) {
        #pragma unroll
        for (int reg = 0; reg < 4; ++reg) {
            const int row = row0 + (lane >> 4) * 4 + reg;
            const int col = nt * 16 + (lane & 15);
            support[(size_t)row * D_OUT + col] = acc[nt][reg];
        }
    }
}

// ---------------------------------------------------------------------------
// Kernel 2: histogram of destination rows (int atomics into counts[]).
// ---------------------------------------------------------------------------
__global__ __launch_bounds__(256) void hist_kernel(const int* __restrict__ rows,
                                                   int* __restrict__ counts) {
    const int e = blockIdx.x * 256 + threadIdx.x;
    if (e < N_EDGES) atomicAdd(&counts[rows[e]], 1);
}

// ---------------------------------------------------------------------------
// Kernel 3a: per-block exclusive scan (Hillis-Steele in LDS), emit block sums.
// ---------------------------------------------------------------------------
__global__ __launch_bounds__(SCAN_BLK) void scan1_kernel(const int* __restrict__ counts,
                                                         int* __restrict__ excl_out,
                                                         int* __restrict__ blk_sums) {
    __shared__ int s[SCAN_BLK];
    const int tid = threadIdx.x;
    const int i   = blockIdx.x * SCAN_BLK + tid;
    const int val = (i < N_NODES) ? counts[i] : 0;
    s[tid] = val;
    __syncthreads();
    for (int off = 1; off < SCAN_BLK; off <<= 1) {
        int t = 0;
        if (tid >= off) t = s[tid - off];
        __syncthreads();
        s[tid] += t;
        __syncthreads();
    }
    const int incl = s[tid];
    if (i < N_NODES) excl_out[i] = incl - val;
    if (tid == SCAN_BLK - 1) blk_sums[blockIdx.x] = incl;
}

// ---------------------------------------------------------------------------
// Kernel 3b: scan the 98 block sums (one block of 128).
// ---------------------------------------------------------------------------
__global__ __launch_bounds__(128) void scan2_kernel(int* __restrict__ blk_sums,
                                                    int* __restrict__ blk_prefix) {
    __shared__ int s[128];
    const int tid = threadIdx.x;
    const int val = (tid < SCAN_NBLK) ? blk_sums[tid] : 0;
    s[tid] = val;
    __syncthreads();
    for (int off = 1; off < 128; off <<= 1) {
        int t = 0;
        if (tid >= off) t = s[tid - off];
        __syncthreads();
        s[tid] += t;
        __syncthreads();
    }
    blk_prefix[tid] = s[tid] - val;   // exclusive
}

// ---------------------------------------------------------------------------
// Kernel 3c: add block prefixes -> final offsets; also init cursor copy.
// ---------------------------------------------------------------------------
__global__ __launch_bounds__(SCAN_BLK) void scan3_kernel(int* __restrict__ offsets,
                                                         const int* __restrict__ blk_prefix,
                                                         int* __restrict__ cursor) {
    const int i = blockIdx.x * SCAN_BLK + threadIdx.x;
    if (i < N_NODES) {
        const int off = offsets[i] + blk_prefix[blockIdx.x];
        offsets[i] = off;
        cursor[i]  = off;
    }
    if (i == 0) offsets[N_NODES] = N_EDGES;
}

// ---------------------------------------------------------------------------
// Kernel 4: bucket edges by destination row. Payload packed into ONE 8B
// int2 store per edge (col, val_bits) -> half the scattered cache lines.
// ---------------------------------------------------------------------------
__global__ __launch_bounds__(256) void reorder_kernel(const int*   __restrict__ rows,
                                                      const int*   __restrict__ cols,
                                                      const float* __restrict__ vals,
                                                      int*   __restrict__ cursor,
                                                      int2*  __restrict__ sorted_pack) {
    const int e = blockIdx.x * 256 + threadIdx.x;
    if (e >= N_EDGES) return;
    const int r   = rows[e];
    const int pos = atomicAdd(&cursor[r], 1);
    sorted_pack[pos] = make_int2(cols[e], __float_as_int(vals[e]));
}

// ---------------------------------------------------------------------------
// Kernel 5: per-row gather-reduce + fused ReLU. One wave per row.
// ---------------------------------------------------------------------------
__global__ __launch_bounds__(256) void reduce_kernel(const int*  __restrict__ offsets,
                                                     const int2* __restrict__ sorted_pack,
                                                     const float* __restrict__ support,
                                                     float*       __restrict__ out) {
    const int lane = threadIdx.x & 63;
    int row = blockIdx.x * 4 + (threadIdx.x >> 6);
    row = __builtin_amdgcn_readfirstlane(row);
    if (row >= N_NODES) return;

    const int start = offsets[row];
    const int end   = offsets[row + 1];

    float acc0 = 0.0f, acc1 = 0.0f, acc2 = 0.0f, acc3 = 0.0f;
    int e = start;
    for (; e + 3 < end; e += 4) {
        const int2 p0 = sorted_pack[e];
        const int2 p1 = sorted_pack[e + 1];
        const int2 p2 = sorted_pack[e + 2];
        const int2 p3 = sorted_pack[e + 3];
        acc0 = fmaf(__int_as_float(p0.y), support[(size_t)p0.x * D_OUT + lane], acc0);
        acc1 = fmaf(__int_as_float(p1.y), support[(size_t)p1.x * D_OUT + lane], acc1);
        acc2 = fmaf(__int_as_float(p2.y), support[(size_t)p2.x * D_OUT + lane], acc2);
        acc3 = fmaf(__int_as_float(p3.y), support[(size_t)p3.x * D_OUT + lane], acc3);
    }
    for (; e < end; ++e) {
        const int2 p = sorted_pack[e];
        acc0 = fmaf(__int_as_float(p.y), support[(size_t)p.x * D_OUT + lane], acc0);
    }
    out[(size_t)row * D_OUT + lane] = fmaxf((acc0 + acc1) + (acc2 + acc3), 0.0f);
}

extern "C" void kernel_launch(void* const* d_in, const int* in_sizes, int n_in,
                              void* d_out, int out_size, void* d_ws, size_t ws_size,
                              hipStream_t stream) {
    const float* feat = (const float*)d_in[0];
    const float* W    = (const float*)d_in[1];
    const int*   rows = (const int*)d_in[2];
    const int*   cols = (const int*)d_in[3];
    const float* vals = (const float*)d_in[4];
    float*       out  = (float*)d_out;

    // Workspace layout (support first; cumulative int offset before
    // sorted_pack is 6,600,360 ints = 26,401,440 B, divisible by 8).
    float* support    = (float*)d_ws;                       // 6,400,000 f
    int*   offsets    = (int*)(support + 6400000);          // 100,004
    int*   cursor     = (int*)(offsets + 100004);           // 100,000 (also histogram)
    int*   blk_sums   = (int*)(cursor + 100000);            // 128
    int*   blk_prefix = (int*)(blk_sums + 128);             // 128
    int2*  sorted_pack = (int2*)(blk_prefix + 128);         // 1,600,000 x 8B

    // 1) dense GEMM (bf16 MFMA)
    gemm_kernel<<<(N_NODES + 63) / 64, 256, 0, stream>>>(feat, W, support);

    // 2) CSR build
    hipMemsetAsync(cursor, 0, N_NODES * sizeof(int), stream);
    hist_kernel<<<(N_EDGES + 255) / 256, 256, 0, stream>>>(rows, cursor);
    scan1_kernel<<<SCAN_NBLK, SCAN_BLK, 0, stream>>>(cursor, offsets, blk_sums);
    scan2_kernel<<<1, 128, 0, stream>>>(blk_sums, blk_prefix);
    scan3_kernel<<<SCAN_NBLK, SCAN_BLK, 0, stream>>>(offsets, blk_prefix, cursor);

    // 3) bucket edges by row (packed payload)
    reorder_kernel<<<(N_EDGES + 255) / 256, 256, 0, stream>>>(rows, cols, vals,
                                                              cursor, sorted_pack);

    // 4) per-row gather-reduce + ReLU
    reduce_kernel<<<(N_NODES + 3) / 4, 256, 0, stream>>>(offsets, sorted_pack,
                                                         support, out);
}